// Round 5
// baseline (462.640 us; speedup 1.0000x reference)
//
#include <hip/hip_runtime.h>
#include <hip/hip_bf16.h>

typedef __attribute__((ext_vector_type(8))) short short8;
typedef __attribute__((ext_vector_type(4))) short short4v;
typedef __attribute__((ext_vector_type(4))) float f32x4;

#define B_ 2
#define S_ 2048
#define HID_ 2048
#define H_ 16
#define KV_ 8
#define D_ 128
#define SCALE_ 0.08838834764831845f

__device__ inline short f2bf(float f) {
    union { __hip_bfloat16 h; short s; } u;
    u.h = __float2bfloat16(f);
    return u.s;
}
__device__ inline float bf2f(short s) {
    union { short s; __hip_bfloat16 h; } u;
    u.s = s;
    return __bfloat162float(u.h);
}

// async global->LDS, 16B per lane; LDS dest is wave-uniform base + lane*16
__device__ inline void gld16(const short* g, short* l) {
    __builtin_amdgcn_global_load_lds(
        (const __attribute__((address_space(1))) unsigned int*)g,
        (__attribute__((address_space(3))) unsigned int*)l, 16, 0, 0);
}

// ---------------- merged prep: all fp32->bf16 conversions + cos/sin mix --
__device__ inline int mrope_axis(int d) {
    int m = d & 63;
    return m < 21 ? 0 : (m < 42 ? 1 : 2);
}
__global__ __launch_bounds__(256) void prep(const float* __restrict__ hid,
                                            const float* __restrict__ qw_,
                                            const float* __restrict__ kw_,
                                            const float* __restrict__ vw_,
                                            const float* __restrict__ ow_,
                                            const float* __restrict__ cosp,
                                            const float* __restrict__ sinp,
                                            short* __restrict__ Hb,
                                            short* __restrict__ Wqkv,
                                            short* __restrict__ Owb,
                                            float* __restrict__ cm,
                                            float* __restrict__ sm) {
    int bid = blockIdx.x;
    if (bid < 20480) {
        const float* src; short* dst; int base;
        if (bid < 8192)       { src = hid; dst = Hb;              base = bid; }
        else if (bid < 12288) { src = qw_; dst = Wqkv;            base = bid - 8192; }
        else if (bid < 14336) { src = kw_; dst = Wqkv + 4194304;  base = bid - 12288; }
        else if (bid < 16384) { src = vw_; dst = Wqkv + 6291456;  base = bid - 14336; }
        else                  { src = ow_; dst = Owb;             base = bid - 16384; }
        int i = base * 1024 + threadIdx.x * 4;
        float4 v = *(const float4*)(&src[i]);
        short4v o;
        o.x = f2bf(v.x); o.y = f2bf(v.y); o.z = f2bf(v.z); o.w = f2bf(v.w);
        *(short4v*)(&dst[i]) = o;
    } else {
        const size_t AX = (size_t)B_ * S_ * D_;
        int i0 = (bid - 20480) * 1024 + threadIdx.x * 4;
#pragma unroll
        for (int k = 0; k < 4; ++k) {
            int idx = i0 + k;
            int d = idx & (D_ - 1);
            size_t src = (size_t)mrope_axis(d) * AX + idx;
            cm[idx] = cosp[src];
            sm[idx] = sinp[src];
        }
    }
}

// ---------------- generic bf16 GEMM (B^T), fp32 out (O-projection) -------
// 128x128 tile, BK=64, gld16 staging with XOR-swizzled granules (conflict-free)
__global__ __launch_bounds__(256) void gemm_bt(const short* __restrict__ A,
                                               const short* __restrict__ B,
                                               float* __restrict__ C,
                                               int M, int N, int K) {
    __shared__ __align__(16) short As[128 * 64];
    __shared__ __align__(16) short Bs[128 * 64];
    int tid = threadIdx.x;
    int wave = tid >> 6, lane = tid & 63;
    int m16 = lane & 15, quad = lane >> 4;
    int wr = wave >> 1, wc = wave & 1;
    int m0 = blockIdx.y * 128, n0 = blockIdx.x * 128;
    int srow = lane >> 3;                       // 0..7 row within 8-row issue
    int scol = ((lane & 7) ^ srow) << 3;        // swizzled source granule (shorts)
    f32x4 acc[4][4] = {};
    for (int k0 = 0; k0 < K; k0 += 64) {
#pragma unroll
        for (int i = 0; i < 4; ++i) {
            gld16(&A[(size_t)(m0 + wave * 32 + i * 8 + srow) * K + k0 + scol],
                  &As[(wave * 32 + i * 8) * 64]);
            gld16(&B[(size_t)(n0 + wave * 32 + i * 8 + srow) * K + k0 + scol],
                  &Bs[(wave * 32 + i * 8) * 64]);
        }
        __syncthreads();
        short8 a[4][2], b[4][2];
#pragma unroll
        for (int i = 0; i < 4; ++i)
#pragma unroll
            for (int kk = 0; kk < 2; ++kk) {
                int gsw = (((kk << 2) + quad) ^ (m16 & 7)) << 3;
                a[i][kk] = *(const short8*)(&As[(wr * 64 + i * 16 + m16) * 64 + gsw]);
                b[i][kk] = *(const short8*)(&Bs[(wc * 64 + i * 16 + m16) * 64 + gsw]);
            }
#pragma unroll
        for (int kk = 0; kk < 2; ++kk)
#pragma unroll
            for (int i = 0; i < 4; ++i)
#pragma unroll
                for (int j = 0; j < 4; ++j)
                    acc[i][j] = __builtin_amdgcn_mfma_f32_16x16x32_bf16(a[i][kk], b[j][kk],
                                                                        acc[i][j], 0, 0, 0);
        __syncthreads();
    }
#pragma unroll
    for (int i = 0; i < 4; ++i) {
        int row = m0 + wr * 64 + i * 16 + quad * 4;
#pragma unroll
        for (int j = 0; j < 4; ++j) {
            int col = n0 + wc * 64 + j * 16 + m16;
#pragma unroll
            for (int r = 0; r < 4; ++r)
                C[(size_t)(row + r) * N + col] = acc[i][j][r];
        }
    }
}

// ---------------- fused QKV GEMM + RMSNorm + mRoPE + V-transpose ---------
#define TP 136
__global__ __launch_bounds__(256) void qkv_fused(const short* __restrict__ A,
                                                 const short* __restrict__ Bw,
                                                 const float* __restrict__ qnw,
                                                 const float* __restrict__ knw,
                                                 const float* __restrict__ cm,
                                                 const float* __restrict__ sm,
                                                 short* __restrict__ Qb,
                                                 short* __restrict__ Kb,
                                                 short* __restrict__ Vb) {
    __shared__ __align__(16) char smem[36864];
    short* As = (short*)smem;                    // 16384 B (K-loop)
    short* Bs = (short*)(smem + 16384);          // 16384 B (K-loop)
    short* T  = (short*)smem;                    // 34816 B (epilogue, unioned)
    float* partial = (float*)(smem + 34816);     // 1024 B
    float* rsA     = (float*)(smem + 35840);     // 512 B
    const int K = HID_;
    int tid = threadIdx.x;
    int wave = tid >> 6, lane = tid & 63;
    int m16 = lane & 15, quad = lane >> 4;
    int wr = wave >> 1, wc = wave & 1;
    int m0 = blockIdx.y * 128, n0 = blockIdx.x * 128;
    int hk = blockIdx.x;                 // 0..15 q, 16..23 k, 24..31 v
    int srow = lane >> 3;
    int scol = ((lane & 7) ^ srow) << 3;
    f32x4 acc[4][4] = {};
    for (int k0 = 0; k0 < K; k0 += 64) {
#pragma unroll
        for (int i = 0; i < 4; ++i) {
            gld16(&A[(size_t)(m0 + wave * 32 + i * 8 + srow) * K + k0 + scol],
                  &As[(wave * 32 + i * 8) * 64]);
            gld16(&Bw[(size_t)(n0 + wave * 32 + i * 8 + srow) * K + k0 + scol],
                  &Bs[(wave * 32 + i * 8) * 64]);
        }
        __syncthreads();
        short8 a[4][2], b[4][2];
#pragma unroll
        for (int i = 0; i < 4; ++i)
#pragma unroll
            for (int kk = 0; kk < 2; ++kk) {
                int gsw = (((kk << 2) + quad) ^ (m16 & 7)) << 3;
                a[i][kk] = *(const short8*)(&As[(wr * 64 + i * 16 + m16) * 64 + gsw]);
                b[i][kk] = *(const short8*)(&Bs[(wc * 64 + i * 16 + m16) * 64 + gsw]);
            }
#pragma unroll
        for (int kk = 0; kk < 2; ++kk)
#pragma unroll
            for (int i = 0; i < 4; ++i)
#pragma unroll
                for (int j = 0; j < 4; ++j)
                    acc[i][j] = __builtin_amdgcn_mfma_f32_16x16x32_bf16(a[i][kk], b[j][kk],
                                                                        acc[i][j], 0, 0, 0);
        __syncthreads();
    }
    int b = m0 >> 11, s0 = m0 & (S_ - 1);
    if (hk >= 24) {
        int kv = hk - 24;
#pragma unroll
        for (int i = 0; i < 4; ++i)
#pragma unroll
            for (int j = 0; j < 4; ++j) {
                short4v v4;
#pragma unroll
                for (int r = 0; r < 4; ++r) v4[r] = f2bf(acc[i][j][r]);
                *(short4v*)&T[(wc * 64 + j * 16 + m16) * TP + wr * 64 + i * 16 + quad * 4] = v4;
            }
        __syncthreads();
        size_t vb = ((size_t)(b * KV_ + kv)) * D_;
#pragma unroll
        for (int it = 0; it < 8; ++it) {
            int e = (it * 256 + tid) * 8;
            int dcol = e >> 7, srw = e & 127;
            *(short8*)&Vb[(vb + dcol) * S_ + s0 + srw] = *(const short8*)&T[dcol * TP + srw];
        }
    } else {
#pragma unroll
        for (int i = 0; i < 4; ++i)
#pragma unroll
            for (int r = 0; r < 4; ++r) {
                float t = 0.f;
#pragma unroll
                for (int j = 0; j < 4; ++j) t += acc[i][j][r] * acc[i][j][r];
#pragma unroll
                for (int msk = 8; msk >= 1; msk >>= 1) t += __shfl_xor(t, msk, 64);
                if (m16 == 0) partial[wc * 128 + wr * 64 + i * 16 + quad * 4 + r] = t;
            }
#pragma unroll
        for (int i = 0; i < 4; ++i)
#pragma unroll
            for (int j = 0; j < 4; ++j)
#pragma unroll
                for (int r = 0; r < 4; ++r)
                    T[(wr * 64 + i * 16 + quad * 4 + r) * TP + wc * 64 + j * 16 + m16] =
                        f2bf(acc[i][j][r]);
        __syncthreads();
        if (tid < 128) {
            float tot = partial[tid] + partial[128 + tid];
            rsA[tid] = rsqrtf(tot * (1.0f / 128.0f) + 1e-6f);
        }
        __syncthreads();
        const float* nw = (hk < 16) ? qnw : knw;
        short* outp = (hk < 16) ? (Qb + ((size_t)(b * H_ + hk)) * S_ * D_)
                                : (Kb + ((size_t)(b * KV_ + hk - 16)) * S_ * D_);
        size_t cmb = ((size_t)(b * S_ + s0)) * D_;
#pragma unroll
        for (int it = 0; it < 8; ++it) {
            int e = (it * 256 + tid) * 8;
            int row = e >> 7, colc = e & 127;
            int pc = colc ^ 64;
            float rs = rsA[row];
            float sg = (colc < 64) ? -1.f : 1.f;
            short8 nv = *(const short8*)&T[row * TP + colc];
            short8 pv = *(const short8*)&T[row * TP + pc];
            float4 cA = *(const float4*)&cm[cmb + (size_t)row * D_ + colc];
            float4 cB = *(const float4*)&cm[cmb + (size_t)row * D_ + colc + 4];
            float4 sA = *(const float4*)&sm[cmb + (size_t)row * D_ + colc];
            float4 sB = *(const float4*)&sm[cmb + (size_t)row * D_ + colc + 4];
            float4 wA = *(const float4*)&nw[colc];
            float4 wB = *(const float4*)&nw[colc + 4];
            float4 wpA = *(const float4*)&nw[pc];
            float4 wpB = *(const float4*)&nw[pc + 4];
            float cs[8] = {cA.x, cA.y, cA.z, cA.w, cB.x, cB.y, cB.z, cB.w};
            float sn[8] = {sA.x, sA.y, sA.z, sA.w, sB.x, sB.y, sB.z, sB.w};
            float wv[8] = {wA.x, wA.y, wA.z, wA.w, wB.x, wB.y, wB.z, wB.w};
            float wp[8] = {wpA.x, wpA.y, wpA.z, wpA.w, wpB.x, wpB.y, wpB.z, wpB.w};
            short8 o;
#pragma unroll
            for (int k = 0; k < 8; ++k) {
                float x = bf2f(nv[k]) * rs * wv[k];
                float p = bf2f(pv[k]) * rs * wp[k];
                o[k] = f2bf(x * cs[k] + sg * p * sn[k]);
            }
            *(short8*)&outp[(size_t)(s0 + row) * D_ + colc] = o;
        }
    }
}

// ---------------- flash attention (causal, GQA), transposed-S form -------
// V frags read directly from global (contiguous 16B, L1/L2-resident);
// only K staged in LDS (padded, conflict-free); P via wave-private LDS.
#define KPAD 136
#define VPAD 72
__global__ __launch_bounds__(256) void attn_fa(const short* __restrict__ Qb,
                                               const short* __restrict__ Kb,
                                               const short* __restrict__ Vb,
                                               short* __restrict__ Ab) {
    __shared__ __align__(16) short Ks[64 * KPAD];
    __shared__ __align__(16) short Ps[4][16 * VPAD];
    int tid = threadIdx.x;
    int wave = tid >> 6, lane = tid & 63;
    int m16 = lane & 15, quad = lane >> 4;
    int bh = blockIdx.x;
    int h = bh & 15, b = bh >> 4;
    int qt = 31 - blockIdx.y;          // heavy causal tiles dispatch first
    int kv = h >> 1;
    const short* Qp = Qb + (size_t)(b * H_ + h) * S_ * D_;
    const short* Kp = Kb + (size_t)(b * KV_ + kv) * S_ * D_;
    const short* Vp = Vb + (size_t)(b * KV_ + kv) * D_ * S_;
    int q_base = qt * 64 + wave * 16;
    int qrow = q_base + m16;           // this lane's q row
    short8 qf[4];
#pragma unroll
    for (int c = 0; c < 4; ++c)
        qf[c] = *(const short8*)(&Qp[(size_t)(q_base + m16) * D_ + c * 32 + quad * 8]);
    f32x4 o_acc[8] = {};               // O^T: row d = j*16+quad*4+r, col q = m16
    float m_r = -1e30f, l_r = 0.f;     // per-lane state for q = m16
    int nchunks = qt + 1;
    for (int kc = 0; kc < nchunks; ++kc) {
        int k0 = kc * 64;
#pragma unroll
        for (int it = 0; it < 4; ++it) {
            int cc = tid + it * 256;
            int row = cc >> 4, col = (cc & 15) * 8;
            *(uint4*)(&Ks[row * KPAD + col]) = *(const uint4*)(&Kp[(size_t)(k0 + row) * D_ + col]);
        }
        __syncthreads();
        // S^T: 4 key tiles of 16; mfma(a=K, b=Q) => row=key, col=q
        float sv[4][4];
#pragma unroll
        for (int nt = 0; nt < 4; ++nt) {
            f32x4 facc = {};
#pragma unroll
            for (int c = 0; c < 4; ++c) {
                short8 kfr = *(const short8*)(&Ks[(nt * 16 + m16) * KPAD + c * 32 + quad * 8]);
                facc = __builtin_amdgcn_mfma_f32_16x16x32_bf16(kfr, qf[c], facc, 0, 0, 0);
            }
            if (kc == qt) {
#pragma unroll
                for (int r = 0; r < 4; ++r) {
                    int key = k0 + nt * 16 + quad * 4 + r;
                    sv[nt][r] = (key <= qrow) ? facc[r] * SCALE_ : -1e30f;
                }
            } else {
#pragma unroll
                for (int r = 0; r < 4; ++r) sv[nt][r] = facc[r] * SCALE_;
            }
        }
        // online softmax: all 16 scores in this lane belong to q = m16
        float mx = -1e30f;
#pragma unroll
        for (int nt = 0; nt < 4; ++nt)
#pragma unroll
            for (int r = 0; r < 4; ++r) mx = fmaxf(mx, sv[nt][r]);
        mx = fmaxf(mx, __shfl_xor(mx, 16, 64));
        mx = fmaxf(mx, __shfl_xor(mx, 32, 64));
        float m_new = fmaxf(m_r, mx);
        float alpha = __expf(m_r - m_new);
        float p[4][4], sum = 0.f;
#pragma unroll
        for (int nt = 0; nt < 4; ++nt)
#pragma unroll
            for (int r = 0; r < 4; ++r) { p[nt][r] = __expf(sv[nt][r] - m_new); sum += p[nt][r]; }
        sum += __shfl_xor(sum, 16, 64);
        sum += __shfl_xor(sum, 32, 64);
        l_r = l_r * alpha + sum;
        m_r = m_new;
#pragma unroll
        for (int j = 0; j < 8; ++j) {
            f32x4 t = o_acc[j];
#pragma unroll
            for (int r = 0; r < 4; ++r) t[r] *= alpha;
            o_acc[j] = t;
        }
        // P store: lane holds P[q=m16][key nt*16+quad*4 .. +3] -> one b64 per nt
#pragma unroll
        for (int nt = 0; nt < 4; ++nt) {
            short4v pk;
#pragma unroll
            for (int r = 0; r < 4; ++r) pk[r] = f2bf(p[nt][r]);
            *(short4v*)&Ps[wave][m16 * VPAD + nt * 16 + quad * 4] = pk;
        }
        // O^T += mfma(a=V^T-frag(global), b=P-frag): two K=32 sub-chunks
#pragma unroll
        for (int kk = 0; kk < 2; ++kk) {
            short8 pf = *(const short8*)(&Ps[wave][m16 * VPAD + kk * 32 + quad * 8]);
#pragma unroll
            for (int j = 0; j < 8; ++j) {
                short8 vfr = *(const short8*)(&Vp[(size_t)(j * 16 + m16) * S_ + k0 + kk * 32 + quad * 8]);
                o_acc[j] = __builtin_amdgcn_mfma_f32_16x16x32_bf16(vfr, pf, o_acc[j], 0, 0, 0);
            }
        }
        __syncthreads();
    }
    // epilogue: lane holds O^T[d = j*16+quad*4+r][q = m16]
    float inv_l = 1.0f / l_r;
    size_t base = ((size_t)(b * S_ + qrow)) * (H_ * D_) + h * D_;
#pragma unroll
    for (int j = 0; j < 8; ++j) {
        short4v ov;
#pragma unroll
        for (int r = 0; r < 4; ++r) ov[r] = f2bf(o_acc[j][r] * inv_l);
        *(short4v*)&Ab[base + j * 16 + quad * 4] = ov;
    }
}

// -------------------------------------------------------------------------
extern "C" void kernel_launch(void* const* d_in, const int* in_sizes, int n_in,
                              void* d_out, int out_size, void* d_ws, size_t ws_size,
                              hipStream_t stream) {
    const float* hid  = (const float*)d_in[0];
    const float* cosp = (const float*)d_in[1];
    const float* sinp = (const float*)d_in[2];
    const float* q_w  = (const float*)d_in[3];
    const float* k_w  = (const float*)d_in[4];
    const float* v_w  = (const float*)d_in[5];
    const float* o_w  = (const float*)d_in[6];
    const float* qnw  = (const float*)d_in[7];
    const float* knw  = (const float*)d_in[8];

    char* w = (char*)d_ws;
    short* Hb    = (short*)w;  w += (size_t)4096 * 2048 * 2;              // 16MB
    short* Wqkv  = (short*)w;  w += (size_t)4096 * 2048 * 2;              // 16MB
    short* Owb   = (short*)w;  w += (size_t)2048 * 2048 * 2;              // 8MB
    short* Qb    = (short*)w;  w += (size_t)B_ * H_ * S_ * D_ * 2;        // 16MB
    short* Kb    = (short*)w;  w += (size_t)B_ * KV_ * S_ * D_ * 2;       // 8MB
    short* Vb    = (short*)w;  w += (size_t)B_ * KV_ * D_ * S_ * 2;       // 8MB
    short* Ab    = (short*)w;  w += (size_t)4096 * 2048 * 2;              // 16MB
    float* cos_m = (float*)w;  w += (size_t)B_ * S_ * D_ * 4;             // 2MB
    float* sin_m = (float*)w;  w += (size_t)B_ * S_ * D_ * 4;             // 2MB

    // 1. single prep kernel: all bf16 conversions + mrope cos/sin premix
    prep<<<20992, 256, 0, stream>>>(hid, q_w, k_w, v_w, o_w, cosp, sinp,
                                    Hb, Wqkv, Owb, cos_m, sin_m);

    // 2. fused QKV GEMM + RMSNorm + mRoPE + V-transpose -> Qb/Kb/Vb bf16
    qkv_fused<<<dim3(32, 32), 256, 0, stream>>>(Hb, Wqkv, qnw, knw, cos_m, sin_m,
                                                Qb, Kb, Vb);

    // 3. flash attention (transposed-S form) -> Ab [B,S,H*D] bf16
    attn_fa<<<dim3(32, 32), 256, 0, stream>>>(Qb, Kb, Vb, Ab);

    // 4. O projection: [4096 x 2048] x [2048 x 2048]^T -> d_out fp32
    gemm_bt<<<dim3(16, 32), 256, 0, stream>>>(Ab, Owb, (float*)d_out, 4096, 2048, 2048);
}

// Round 6
// 352.670 us; speedup vs baseline: 1.3118x; 1.3118x over previous
//
#include <hip/hip_runtime.h>
#include <hip/hip_bf16.h>

typedef __attribute__((ext_vector_type(8))) short short8;
typedef __attribute__((ext_vector_type(4))) short short4v;
typedef __attribute__((ext_vector_type(4))) float f32x4;

#define B_ 2
#define S_ 2048
#define HID_ 2048
#define H_ 16
#define KV_ 8
#define D_ 128
#define SCALE_ 0.08838834764831845f

__device__ inline short f2bf(float f) {
    union { __hip_bfloat16 h; short s; } u;
    u.h = __float2bfloat16(f);
    return u.s;
}
__device__ inline float bf2f(short s) {
    union { short s; __hip_bfloat16 h; } u;
    u.s = s;
    return __bfloat162float(u.h);
}

// async global->LDS, 16B per lane; LDS dest is wave-uniform base + lane*16
__device__ inline void gld16(const short* g, short* l) {
    __builtin_amdgcn_global_load_lds(
        (const __attribute__((address_space(1))) unsigned int*)g,
        (__attribute__((address_space(3))) unsigned int*)l, 16, 0, 0);
}

// ---------------- merged prep: all fp32->bf16 conversions + cos/sin mix --
__device__ inline int mrope_axis(int d) {
    int m = d & 63;
    return m < 21 ? 0 : (m < 42 ? 1 : 2);
}
__global__ __launch_bounds__(256) void prep(const float* __restrict__ hid,
                                            const float* __restrict__ qw_,
                                            const float* __restrict__ kw_,
                                            const float* __restrict__ vw_,
                                            const float* __restrict__ ow_,
                                            const float* __restrict__ cosp,
                                            const float* __restrict__ sinp,
                                            short* __restrict__ Hb,
                                            short* __restrict__ Wqkv,
                                            short* __restrict__ Owb,
                                            float* __restrict__ cm,
                                            float* __restrict__ sm) {
    int bid = blockIdx.x;
    if (bid < 20480) {
        const float* src; short* dst; int base;
        if (bid < 8192)       { src = hid; dst = Hb;              base = bid; }
        else if (bid < 12288) { src = qw_; dst = Wqkv;            base = bid - 8192; }
        else if (bid < 14336) { src = kw_; dst = Wqkv + 4194304;  base = bid - 12288; }
        else if (bid < 16384) { src = vw_; dst = Wqkv + 6291456;  base = bid - 14336; }
        else                  { src = ow_; dst = Owb;             base = bid - 16384; }
        int i = base * 1024 + threadIdx.x * 4;
        float4 v = *(const float4*)(&src[i]);
        short4v o;
        o.x = f2bf(v.x); o.y = f2bf(v.y); o.z = f2bf(v.z); o.w = f2bf(v.w);
        *(short4v*)(&dst[i]) = o;
    } else {
        const size_t AX = (size_t)B_ * S_ * D_;
        int i0 = (bid - 20480) * 1024 + threadIdx.x * 4;
#pragma unroll
        for (int k = 0; k < 4; ++k) {
            int idx = i0 + k;
            int d = idx & (D_ - 1);
            size_t src = (size_t)mrope_axis(d) * AX + idx;
            cm[idx] = cosp[src];
            sm[idx] = sinp[src];
        }
    }
}

// ---------------- generic bf16 GEMM (B^T), fp32 out (O-projection) -------
// 128x128 tile, BK=64, gld16 staging with XOR-swizzled granules (conflict-free)
__global__ __launch_bounds__(256) void gemm_bt(const short* __restrict__ A,
                                               const short* __restrict__ B,
                                               float* __restrict__ C,
                                               int M, int N, int K) {
    __shared__ __align__(16) short As[128 * 64];
    __shared__ __align__(16) short Bs[128 * 64];
    int tid = threadIdx.x;
    int wave = tid >> 6, lane = tid & 63;
    int m16 = lane & 15, quad = lane >> 4;
    int wr = wave >> 1, wc = wave & 1;
    int m0 = blockIdx.y * 128, n0 = blockIdx.x * 128;
    int srow = lane >> 3;                       // 0..7 row within 8-row issue
    int scol = ((lane & 7) ^ srow) << 3;        // swizzled source granule (shorts)
    f32x4 acc[4][4] = {};
    for (int k0 = 0; k0 < K; k0 += 64) {
#pragma unroll
        for (int i = 0; i < 4; ++i) {
            gld16(&A[(size_t)(m0 + wave * 32 + i * 8 + srow) * K + k0 + scol],
                  &As[(wave * 32 + i * 8) * 64]);
            gld16(&B[(size_t)(n0 + wave * 32 + i * 8 + srow) * K + k0 + scol],
                  &Bs[(wave * 32 + i * 8) * 64]);
        }
        __syncthreads();
        short8 a[4][2], b[4][2];
#pragma unroll
        for (int i = 0; i < 4; ++i)
#pragma unroll
            for (int kk = 0; kk < 2; ++kk) {
                int gsw = (((kk << 2) + quad) ^ (m16 & 7)) << 3;
                a[i][kk] = *(const short8*)(&As[(wr * 64 + i * 16 + m16) * 64 + gsw]);
                b[i][kk] = *(const short8*)(&Bs[(wc * 64 + i * 16 + m16) * 64 + gsw]);
            }
#pragma unroll
        for (int kk = 0; kk < 2; ++kk)
#pragma unroll
            for (int i = 0; i < 4; ++i)
#pragma unroll
                for (int j = 0; j < 4; ++j)
                    acc[i][j] = __builtin_amdgcn_mfma_f32_16x16x32_bf16(a[i][kk], b[j][kk],
                                                                        acc[i][j], 0, 0, 0);
        __syncthreads();
    }
#pragma unroll
    for (int i = 0; i < 4; ++i) {
        int row = m0 + wr * 64 + i * 16 + quad * 4;
#pragma unroll
        for (int j = 0; j < 4; ++j) {
            int col = n0 + wc * 64 + j * 16 + m16;
#pragma unroll
            for (int r = 0; r < 4; ++r)
                C[(size_t)(row + r) * N + col] = acc[i][j][r];
        }
    }
}

// ---------------- fused QKV GEMM + RMSNorm + mRoPE + V-transpose ---------
#define TP 136
__global__ __launch_bounds__(256) void qkv_fused(const short* __restrict__ A,
                                                 const short* __restrict__ Bw,
                                                 const float* __restrict__ qnw,
                                                 const float* __restrict__ knw,
                                                 const float* __restrict__ cm,
                                                 const float* __restrict__ sm,
                                                 short* __restrict__ Qb,
                                                 short* __restrict__ Kb,
                                                 short* __restrict__ Vb) {
    __shared__ __align__(16) char smem[36864];
    short* As = (short*)smem;                    // 16384 B (K-loop)
    short* Bs = (short*)(smem + 16384);          // 16384 B (K-loop)
    short* T  = (short*)smem;                    // 34816 B (epilogue, unioned)
    float* partial = (float*)(smem + 34816);     // 1024 B
    float* rsA     = (float*)(smem + 35840);     // 512 B
    const int K = HID_;
    int tid = threadIdx.x;
    int wave = tid >> 6, lane = tid & 63;
    int m16 = lane & 15, quad = lane >> 4;
    int wr = wave >> 1, wc = wave & 1;
    int m0 = blockIdx.y * 128, n0 = blockIdx.x * 128;
    int hk = blockIdx.x;                 // 0..15 q, 16..23 k, 24..31 v
    int srow = lane >> 3;
    int scol = ((lane & 7) ^ srow) << 3;
    f32x4 acc[4][4] = {};
    for (int k0 = 0; k0 < K; k0 += 64) {
#pragma unroll
        for (int i = 0; i < 4; ++i) {
            gld16(&A[(size_t)(m0 + wave * 32 + i * 8 + srow) * K + k0 + scol],
                  &As[(wave * 32 + i * 8) * 64]);
            gld16(&Bw[(size_t)(n0 + wave * 32 + i * 8 + srow) * K + k0 + scol],
                  &Bs[(wave * 32 + i * 8) * 64]);
        }
        __syncthreads();
        short8 a[4][2], b[4][2];
#pragma unroll
        for (int i = 0; i < 4; ++i)
#pragma unroll
            for (int kk = 0; kk < 2; ++kk) {
                int gsw = (((kk << 2) + quad) ^ (m16 & 7)) << 3;
                a[i][kk] = *(const short8*)(&As[(wr * 64 + i * 16 + m16) * 64 + gsw]);
                b[i][kk] = *(const short8*)(&Bs[(wc * 64 + i * 16 + m16) * 64 + gsw]);
            }
#pragma unroll
        for (int kk = 0; kk < 2; ++kk)
#pragma unroll
            for (int i = 0; i < 4; ++i)
#pragma unroll
                for (int j = 0; j < 4; ++j)
                    acc[i][j] = __builtin_amdgcn_mfma_f32_16x16x32_bf16(a[i][kk], b[j][kk],
                                                                        acc[i][j], 0, 0, 0);
        __syncthreads();
    }
    int b = m0 >> 11, s0 = m0 & (S_ - 1);
    if (hk >= 24) {
        int kv = hk - 24;
#pragma unroll
        for (int i = 0; i < 4; ++i)
#pragma unroll
            for (int j = 0; j < 4; ++j) {
                short4v v4;
#pragma unroll
                for (int r = 0; r < 4; ++r) v4[r] = f2bf(acc[i][j][r]);
                *(short4v*)&T[(wc * 64 + j * 16 + m16) * TP + wr * 64 + i * 16 + quad * 4] = v4;
            }
        __syncthreads();
        size_t vb = ((size_t)(b * KV_ + kv)) * D_;
#pragma unroll
        for (int it = 0; it < 8; ++it) {
            int e = (it * 256 + tid) * 8;
            int dcol = e >> 7, srw = e & 127;
            *(short8*)&Vb[(vb + dcol) * S_ + s0 + srw] = *(const short8*)&T[dcol * TP + srw];
        }
    } else {
#pragma unroll
        for (int i = 0; i < 4; ++i)
#pragma unroll
            for (int r = 0; r < 4; ++r) {
                float t = 0.f;
#pragma unroll
                for (int j = 0; j < 4; ++j) t += acc[i][j][r] * acc[i][j][r];
#pragma unroll
                for (int msk = 8; msk >= 1; msk >>= 1) t += __shfl_xor(t, msk, 64);
                if (m16 == 0) partial[wc * 128 + wr * 64 + i * 16 + quad * 4 + r] = t;
            }
#pragma unroll
        for (int i = 0; i < 4; ++i)
#pragma unroll
            for (int j = 0; j < 4; ++j)
#pragma unroll
                for (int r = 0; r < 4; ++r)
                    T[(wr * 64 + i * 16 + quad * 4 + r) * TP + wc * 64 + j * 16 + m16] =
                        f2bf(acc[i][j][r]);
        __syncthreads();
        if (tid < 128) {
            float tot = partial[tid] + partial[128 + tid];
            rsA[tid] = rsqrtf(tot * (1.0f / 128.0f) + 1e-6f);
        }
        __syncthreads();
        const float* nw = (hk < 16) ? qnw : knw;
        short* outp = (hk < 16) ? (Qb + ((size_t)(b * H_ + hk)) * S_ * D_)
                                : (Kb + ((size_t)(b * KV_ + hk - 16)) * S_ * D_);
        size_t cmb = ((size_t)(b * S_ + s0)) * D_;
#pragma unroll
        for (int it = 0; it < 8; ++it) {
            int e = (it * 256 + tid) * 8;
            int row = e >> 7, colc = e & 127;
            int pc = colc ^ 64;
            float rs = rsA[row];
            float sg = (colc < 64) ? -1.f : 1.f;
            short8 nv = *(const short8*)&T[row * TP + colc];
            short8 pv = *(const short8*)&T[row * TP + pc];
            float4 cA = *(const float4*)&cm[cmb + (size_t)row * D_ + colc];
            float4 cB = *(const float4*)&cm[cmb + (size_t)row * D_ + colc + 4];
            float4 sA = *(const float4*)&sm[cmb + (size_t)row * D_ + colc];
            float4 sB = *(const float4*)&sm[cmb + (size_t)row * D_ + colc + 4];
            float4 wA = *(const float4*)&nw[colc];
            float4 wB = *(const float4*)&nw[colc + 4];
            float4 wpA = *(const float4*)&nw[pc];
            float4 wpB = *(const float4*)&nw[pc + 4];
            float cs[8] = {cA.x, cA.y, cA.z, cA.w, cB.x, cB.y, cB.z, cB.w};
            float sn[8] = {sA.x, sA.y, sA.z, sA.w, sB.x, sB.y, sB.z, sB.w};
            float wv[8] = {wA.x, wA.y, wA.z, wA.w, wB.x, wB.y, wB.z, wB.w};
            float wp[8] = {wpA.x, wpA.y, wpA.z, wpA.w, wpB.x, wpB.y, wpB.z, wpB.w};
            short8 o;
#pragma unroll
            for (int k = 0; k < 8; ++k) {
                float x = bf2f(nv[k]) * rs * wv[k];
                float p = bf2f(pv[k]) * rs * wp[k];
                o[k] = f2bf(x * cs[k] + sg * p * sn[k]);
            }
            *(short8*)&outp[(size_t)(s0 + row) * D_ + colc] = o;
        }
    }
}

// ---------------- flash attention (causal, GQA), transposed-S form -------
// Round-4 version: K and V both staged in padded LDS (conflict-free);
// S^T = mfma(K,Q) -> per-lane softmax state; P via wave-private LDS;
// O^T = mfma(V,P). Qb [B,H,S,D], Kb [B,KV,S,D], Vb [B,KV,D,S] -> Ab bf16.
#define KPAD 136
#define VPAD 72
__global__ __launch_bounds__(256) void attn_fa(const short* __restrict__ Qb,
                                               const short* __restrict__ Kb,
                                               const short* __restrict__ Vb,
                                               short* __restrict__ Ab) {
    __shared__ __align__(16) short Ks[64 * KPAD];
    __shared__ __align__(16) short Vs[128 * VPAD];
    __shared__ __align__(16) short Ps[4][16 * VPAD];
    int tid = threadIdx.x;
    int wave = tid >> 6, lane = tid & 63;
    int m16 = lane & 15, quad = lane >> 4;
    int bh = blockIdx.x;
    int h = bh & 15, b = bh >> 4;
    int qt = 31 - blockIdx.y;          // heavy causal tiles dispatch first
    int kv = h >> 1;
    const short* Qp = Qb + (size_t)(b * H_ + h) * S_ * D_;
    const short* Kp = Kb + (size_t)(b * KV_ + kv) * S_ * D_;
    const short* Vp = Vb + (size_t)(b * KV_ + kv) * D_ * S_;
    int q_base = qt * 64 + wave * 16;
    int qrow = q_base + m16;           // this lane's q row
    short8 qf[4];
#pragma unroll
    for (int c = 0; c < 4; ++c)
        qf[c] = *(const short8*)(&Qp[(size_t)(q_base + m16) * D_ + c * 32 + quad * 8]);
    f32x4 o_acc[8] = {};               // O^T: row d = j*16+quad*4+r, col q = m16
    float m_r = -1e30f, l_r = 0.f;     // per-lane state for q = m16
    int nchunks = qt + 1;
    for (int kc = 0; kc < nchunks; ++kc) {
        int k0 = kc * 64;
#pragma unroll
        for (int it = 0; it < 4; ++it) {
            int cc = tid + it * 256;
            int row = cc >> 4, col = (cc & 15) * 8;
            *(uint4*)(&Ks[row * KPAD + col]) = *(const uint4*)(&Kp[(size_t)(k0 + row) * D_ + col]);
        }
#pragma unroll
        for (int it = 0; it < 4; ++it) {
            int cc = tid + it * 256;
            int row = cc >> 3, col = (cc & 7) * 8;
            *(uint4*)(&Vs[row * VPAD + col]) = *(const uint4*)(&Vp[(size_t)row * S_ + k0 + col]);
        }
        __syncthreads();
        // S^T: 4 key tiles of 16; mfma(a=K, b=Q) => row=key, col=q
        float sv[4][4];
#pragma unroll
        for (int nt = 0; nt < 4; ++nt) {
            f32x4 facc = {};
#pragma unroll
            for (int c = 0; c < 4; ++c) {
                short8 kfr = *(const short8*)(&Ks[(nt * 16 + m16) * KPAD + c * 32 + quad * 8]);
                facc = __builtin_amdgcn_mfma_f32_16x16x32_bf16(kfr, qf[c], facc, 0, 0, 0);
            }
            if (kc == qt) {
#pragma unroll
                for (int r = 0; r < 4; ++r) {
                    int key = k0 + nt * 16 + quad * 4 + r;
                    sv[nt][r] = (key <= qrow) ? facc[r] * SCALE_ : -1e30f;
                }
            } else {
#pragma unroll
                for (int r = 0; r < 4; ++r) sv[nt][r] = facc[r] * SCALE_;
            }
        }
        // online softmax: all 16 scores in this lane belong to q = m16
        float mx = -1e30f;
#pragma unroll
        for (int nt = 0; nt < 4; ++nt)
#pragma unroll
            for (int r = 0; r < 4; ++r) mx = fmaxf(mx, sv[nt][r]);
        mx = fmaxf(mx, __shfl_xor(mx, 16, 64));
        mx = fmaxf(mx, __shfl_xor(mx, 32, 64));
        float m_new = fmaxf(m_r, mx);
        float alpha = __expf(m_r - m_new);
        float p[4][4], sum = 0.f;
#pragma unroll
        for (int nt = 0; nt < 4; ++nt)
#pragma unroll
            for (int r = 0; r < 4; ++r) { p[nt][r] = __expf(sv[nt][r] - m_new); sum += p[nt][r]; }
        sum += __shfl_xor(sum, 16, 64);
        sum += __shfl_xor(sum, 32, 64);
        l_r = l_r * alpha + sum;
        m_r = m_new;
#pragma unroll
        for (int j = 0; j < 8; ++j) {
            f32x4 t = o_acc[j];
#pragma unroll
            for (int r = 0; r < 4; ++r) t[r] *= alpha;
            o_acc[j] = t;
        }
        // P store: lane holds P[q=m16][key nt*16+quad*4 .. +3] -> one b64 per nt
#pragma unroll
        for (int nt = 0; nt < 4; ++nt) {
            short4v pk;
#pragma unroll
            for (int r = 0; r < 4; ++r) pk[r] = f2bf(p[nt][r]);
            *(short4v*)&Ps[wave][m16 * VPAD + nt * 16 + quad * 4] = pk;
        }
        // O^T += mfma(a=V^T-frag, b=P-frag): two K=32 sub-chunks
#pragma unroll
        for (int kk = 0; kk < 2; ++kk) {
            short8 pf = *(const short8*)(&Ps[wave][m16 * VPAD + kk * 32 + quad * 8]);
#pragma unroll
            for (int j = 0; j < 8; ++j) {
                short8 vfr = *(const short8*)(&Vs[(j * 16 + m16) * VPAD + kk * 32 + quad * 8]);
                o_acc[j] = __builtin_amdgcn_mfma_f32_16x16x32_bf16(vfr, pf, o_acc[j], 0, 0, 0);
            }
        }
        __syncthreads();
    }
    // epilogue: lane holds O^T[d = j*16+quad*4+r][q = m16]
    float inv_l = 1.0f / l_r;
    size_t base = ((size_t)(b * S_ + qrow)) * (H_ * D_) + h * D_;
#pragma unroll
    for (int j = 0; j < 8; ++j) {
        short4v ov;
#pragma unroll
        for (int r = 0; r < 4; ++r) ov[r] = f2bf(o_acc[j][r] * inv_l);
        *(short4v*)&Ab[base + j * 16 + quad * 4] = ov;
    }
}

// -------------------------------------------------------------------------
extern "C" void kernel_launch(void* const* d_in, const int* in_sizes, int n_in,
                              void* d_out, int out_size, void* d_ws, size_t ws_size,
                              hipStream_t stream) {
    const float* hid  = (const float*)d_in[0];
    const float* cosp = (const float*)d_in[1];
    const float* sinp = (const float*)d_in[2];
    const float* q_w  = (const float*)d_in[3];
    const float* k_w  = (const float*)d_in[4];
    const float* v_w  = (const float*)d_in[5];
    const float* o_w  = (const float*)d_in[6];
    const float* qnw  = (const float*)d_in[7];
    const float* knw  = (const float*)d_in[8];

    char* w = (char*)d_ws;
    short* Hb    = (short*)w;  w += (size_t)4096 * 2048 * 2;              // 16MB
    short* Wqkv  = (short*)w;  w += (size_t)4096 * 2048 * 2;              // 16MB
    short* Owb   = (short*)w;  w += (size_t)2048 * 2048 * 2;              // 8MB
    short* Qb    = (short*)w;  w += (size_t)B_ * H_ * S_ * D_ * 2;        // 16MB
    short* Kb    = (short*)w;  w += (size_t)B_ * KV_ * S_ * D_ * 2;       // 8MB
    short* Vb    = (short*)w;  w += (size_t)B_ * KV_ * D_ * S_ * 2;       // 8MB
    short* Ab    = (short*)w;  w += (size_t)4096 * 2048 * 2;              // 16MB
    float* cos_m = (float*)w;  w += (size_t)B_ * S_ * D_ * 4;             // 2MB
    float* sin_m = (float*)w;  w += (size_t)B_ * S_ * D_ * 4;             // 2MB

    // 1. single prep kernel: all bf16 conversions + mrope cos/sin premix
    prep<<<20992, 256, 0, stream>>>(hid, q_w, k_w, v_w, o_w, cosp, sinp,
                                    Hb, Wqkv, Owb, cos_m, sin_m);

    // 2. fused QKV GEMM + RMSNorm + mRoPE + V-transpose -> Qb/Kb/Vb bf16
    qkv_fused<<<dim3(32, 32), 256, 0, stream>>>(Hb, Wqkv, qnw, knw, cos_m, sin_m,
                                                Qb, Kb, Vb);

    // 3. flash attention (transposed-S form) -> Ab [B,S,H*D] bf16
    attn_fa<<<dim3(32, 32), 256, 0, stream>>>(Qb, Kb, Vb, Ab);

    // 4. O projection: [4096 x 2048] x [2048 x 2048]^T -> d_out fp32
    gemm_bt<<<dim3(16, 32), 256, 0, stream>>>(Ab, Owb, (float*)d_out, 4096, 2048, 2048);
}